// Round 14
// baseline (321.734 us; speedup 1.0000x reference)
//
#include <hip/hip_runtime.h>
#include <cstdint>
#include <cstddef>

#define B_ 2
#define S_ 2048
#define NQKV 4096
#define HQ 16
#define HKV 8
#define DH 128
#define KOFF 2048
#define VOFF 3072

typedef __attribute__((ext_vector_type(4))) float f32x4;
typedef __attribute__((ext_vector_type(8))) short bf16x8;
typedef __attribute__((ext_vector_type(4))) unsigned int u32x4;
typedef const __attribute__((address_space(1))) void* gas1;
typedef __attribute__((address_space(3))) void* las3;
typedef __attribute__((address_space(3))) char* l3p;

__device__ __forceinline__ ushort f2b(float f) {
  union { float f; unsigned u; } x; x.f = f;
  return (ushort)((x.u + 0x7FFFu + ((x.u >> 16) & 1u)) >> 16);
}
__device__ __forceinline__ float b2f(ushort u) {
  union { unsigned u; float f; } x; x.u = ((unsigned)u) << 16; return x.f;
}

// ---------------- fused input casts: hs (f32->bf16) + concat(wq,wk,wv) ----------------
__global__ void prep_cast_kernel(const float4* __restrict__ hs,
                                 const float* __restrict__ wq, const float* __restrict__ wk,
                                 const float* __restrict__ wv,
                                 ushort4* __restrict__ xb, ushort4* __restrict__ wcat) {
  int bid = blockIdx.x;
  if (bid < 16384) {
    int i = bid * 256 + threadIdx.x;
    float4 v = hs[i];
    xb[i] = make_ushort4(f2b(v.x), f2b(v.y), f2b(v.z), f2b(v.w));
  } else {
    int i = (bid - 16384) * 256 + threadIdx.x;   // 0 .. 4096*1024
    int row = i >> 10, c4 = i & 1023;
    const float* src = (row < 2048) ? (wq + (size_t)row * 4096)
                     : (row < 3072) ? (wk + (size_t)(row - 2048) * 4096)
                                    : (wv + (size_t)(row - 3072) * 4096);
    float4 v = ((const float4*)src)[c4];
    wcat[i] = make_ushort4(f2b(v.x), f2b(v.y), f2b(v.z), f2b(v.w));
  }
}

// ---------------- GEMM: C[M,N] = A[M,K] * B[N,K]^T  (256x256 8-phase, asm ds_read) ----------------
// R6 schedule (verified fastest). Depth-2 variant measured SLOWER (R7).
#define DSR(dst, addr, off) asm volatile("ds_read_b128 %0, %1 offset:" #off : "=v"(dst) : "v"(addr) : "memory")
#define MFMA16(d, a, b) d = __builtin_amdgcn_mfma_f32_16x16x32_bf16(a, b, d, 0, 0, 0)

template<int OUT_BF16>
__launch_bounds__(512, 2)
__global__ void gemm256(const ushort* __restrict__ A, const ushort* __restrict__ Bm,
                        void* __restrict__ C, int M, int N, int K) {
  __shared__ __attribute__((aligned(16))) char lds[131072];
  const int tid = threadIdx.x;
  const int lane = tid & 63;
  const int w = tid >> 6;          // 0..7
  const int wm = w >> 2, wn = w & 3;
  const int lr = lane & 15, lg = lane >> 4;

  const int nwg = gridDim.x;
  const int cpx = nwg >> 3;
  const int wg = blockIdx.x;
  const int swz = (wg & 7) * cpx + (wg >> 3);
  const int NT = N >> 8;
  const int bm = swz / NT, bn = swz % NT;
  const int m0 = bm * 256, n0 = bn * 256;

  const ushort* Ab = A + (size_t)m0 * K;
  const ushort* Bb = Bm + (size_t)n0 * K;

  const int NKT = K >> 6;          // K-tiles of 64

  int srow[2], scol[2];
#pragma unroll
  for (int jj = 0; jj < 2; ++jj) {
    int lb = (jj * 512 + tid) * 16;
    int ls = lb ^ (((lb >> 7) & 7) << 4);
    srow[jj] = ls >> 7;            // 0..127
    scol[jj] = (ls & 127) >> 1;    // element col 0..63
  }
  const int ldsw = w * 1024;

  auto stage2 = [&](int t, int j) {
    t = (t < NKT - 1) ? t : (NKT - 1);       // tail clamp: re-stage same data (benign)
    const int slot = ((t & 1) << 16) + (j << 14);
    const ushort* src = (j == 1 || j == 2) ? Ab : Bb;
    const int h = (j >= 2) ? 128 : 0;
    const int k0 = t << 6;
#pragma unroll
    for (int jj = 0; jj < 2; ++jj) {
      const ushort* g = src + (size_t)(h + srow[jj]) * K + k0 + scol[jj];
      __builtin_amdgcn_global_load_lds((gas1)(const void*)g,
          (las3)(void*)(lds + slot + jj * 8192 + ldsw), 16, 0, 0);
    }
  };

  const unsigned lds0 = (unsigned)(size_t)(l3p)(void*)lds;
  const int swzc = (lr & 7) << 4;
  const int c0 = (lg * 16) ^ swzc;
  const int c1 = (64 + lg * 16) ^ swzc;
  const unsigned baseA = lds0 + 16384u + wm * 16384u + lr * 128u;
  const unsigned baseB = lds0 + ((wn >> 1) ? 49152u : 0u) + ((wn & 1) * 64 + lr) * 128u;

  f32x4 zero = {0.0f, 0.0f, 0.0f, 0.0f};
  f32x4 acc[8][4];
#pragma unroll
  for (int m = 0; m < 8; ++m)
#pragma unroll
    for (int n = 0; n < 4; ++n) acc[m][n] = zero;

  // prologue: tile0 all four slots + tile1 j0,j1  (12 loads); wait tile0 (youngest 4 may fly)
  stage2(0, 0); stage2(0, 1); stage2(0, 2); stage2(0, 3);
  stage2(1, 0); stage2(1, 1);
  asm volatile("s_waitcnt vmcnt(4)" ::: "memory");
  __builtin_amdgcn_s_barrier();

  for (int kt = 0; kt < NKT; ++kt) {
    const unsigned bo = (unsigned)((kt & 1) << 16);
    const unsigned aak0 = baseA + c0 + bo, aak1 = baseA + c1 + bo;
    const unsigned bak0 = baseB + c0 + bo, bak1 = baseB + c1 + bo;

    bf16x8 a0[2][4], a1[2][4], bq[2][2], bq2[2][2];

    // ---- P0: read a0(8) + b01(4) ; stage (kt+1, j2) ; MFMA Q(0,0)
    DSR(a0[0][0], aak0, 0);    DSR(a0[0][1], aak0, 2048);
    DSR(a0[0][2], aak0, 4096); DSR(a0[0][3], aak0, 6144);
    DSR(a0[1][0], aak1, 0);    DSR(a0[1][1], aak1, 2048);
    DSR(a0[1][2], aak1, 4096); DSR(a0[1][3], aak1, 6144);
    DSR(bq[0][0], bak0, 0);    DSR(bq[0][1], bak0, 2048);
    DSR(bq[1][0], bak1, 0);    DSR(bq[1][1], bak1, 2048);
    stage2(kt + 1, 2);
    asm volatile("s_waitcnt lgkmcnt(8)" ::: "memory");
    __builtin_amdgcn_s_barrier();
    asm volatile("s_waitcnt lgkmcnt(0)" ::: "memory");
    __builtin_amdgcn_sched_barrier(0);
    __builtin_amdgcn_s_setprio(1);
#pragma unroll
    for (int kk = 0; kk < 2; ++kk)
#pragma unroll
      for (int m = 0; m < 4; ++m) {
        MFMA16(acc[m][0], a0[kk][m], bq[kk][0]);
        MFMA16(acc[m][1], a0[kk][m], bq[kk][1]);
      }
    __builtin_amdgcn_s_setprio(0);
    __builtin_amdgcn_s_barrier();

    // ---- P1: read b23(4) ; stage (kt+1, j3) ; MFMA Q(0,1)
    DSR(bq2[0][0], bak0, 4096); DSR(bq2[0][1], bak0, 6144);
    DSR(bq2[1][0], bak1, 4096); DSR(bq2[1][1], bak1, 6144);
    stage2(kt + 1, 3);
    __builtin_amdgcn_s_barrier();
    asm volatile("s_waitcnt lgkmcnt(0)" ::: "memory");
    __builtin_amdgcn_sched_barrier(0);
    __builtin_amdgcn_s_setprio(1);
#pragma unroll
    for (int kk = 0; kk < 2; ++kk)
#pragma unroll
      for (int m = 0; m < 4; ++m) {
        MFMA16(acc[m][2], a0[kk][m], bq2[kk][0]);
        MFMA16(acc[m][3], a0[kk][m], bq2[kk][1]);
      }
    __builtin_amdgcn_s_setprio(0);
    __builtin_amdgcn_s_barrier();

    // ---- P2: read a1(8) ; stage (kt+2, j0) [drained @P1-end] ; MFMA Q(1,0)
    DSR(a1[0][0], aak0, 8192);  DSR(a1[0][1], aak0, 10240);
    DSR(a1[0][2], aak0, 12288); DSR(a1[0][3], aak0, 14336);
    DSR(a1[1][0], aak1, 8192);  DSR(a1[1][1], aak1, 10240);
    DSR(a1[1][2], aak1, 12288); DSR(a1[1][3], aak1, 14336);
    stage2(kt + 2, 0);
    __builtin_amdgcn_s_barrier();
    asm volatile("s_waitcnt lgkmcnt(0)" ::: "memory");
    __builtin_amdgcn_sched_barrier(0);
    __builtin_amdgcn_s_setprio(1);
#pragma unroll
    for (int kk = 0; kk < 2; ++kk)
#pragma unroll
      for (int m = 0; m < 4; ++m) {
        MFMA16(acc[m + 4][0], a1[kk][m], bq[kk][0]);
        MFMA16(acc[m + 4][1], a1[kk][m], bq[kk][1]);
      }
    __builtin_amdgcn_s_setprio(0);
    __builtin_amdgcn_s_barrier();

    // ---- P3: stage (kt+2, j1) [drained @P2-end] ; MFMA Q(1,1) ; vmcnt(4) at tile boundary
    stage2(kt + 2, 1);
    __builtin_amdgcn_s_barrier();
    __builtin_amdgcn_s_setprio(1);
#pragma unroll
    for (int kk = 0; kk < 2; ++kk)
#pragma unroll
      for (int m = 0; m < 4; ++m) {
        MFMA16(acc[m + 4][2], a1[kk][m], bq2[kk][0]);
        MFMA16(acc[m + 4][3], a1[kk][m], bq2[kk][1]);
      }
    __builtin_amdgcn_s_setprio(0);
    asm volatile("s_waitcnt vmcnt(4)" ::: "memory");
    __builtin_amdgcn_s_barrier();
  }

  // drain tail-clamped LDS-DMA before epilogue / endpgm
  asm volatile("s_waitcnt vmcnt(0)" ::: "memory");

  // epilogue
#pragma unroll
  for (int m = 0; m < 8; ++m) {
    const int row0 = m0 + wm * 128 + m * 16 + lg * 4;
#pragma unroll
    for (int n = 0; n < 4; ++n) {
      const int col = n0 + wn * 64 + n * 16 + lr;
#pragma unroll
      for (int r = 0; r < 4; ++r) {
        if (OUT_BF16) ((ushort*)C)[(size_t)(row0 + r) * N + col] = f2b(acc[m][n][r]);
        else          ((float*)C)[(size_t)(row0 + r) * N + col] = acc[m][n][r];
      }
    }
  }
}

// ---------------- fused RoPE (Q/K in-place) + V transpose + wo cast ----------------
__global__ void rope_tv_wo_kernel(ushort* __restrict__ qkv, ushort* __restrict__ vt,
                                  const float4* __restrict__ wo, ushort4* __restrict__ wob) {
  __shared__ ushort tile[32][33];
  int bid = blockIdx.x;
  int tid = threadIdx.x;
  if (bid < 24576) {
    int t = bid * 256 + tid;                 // < 4096*1536
    int row = t / 1536;
    int idx = t - row * 1536;
    int head = idx >> 6, d = idx & 63;
    int pos = row & (S_ - 1);
    int col = (head < HQ) ? (head * DH + d) : (KOFF + (head - HQ) * DH + d);
    size_t base = (size_t)row * NQKV + col;
    float x1 = b2f(qkv[base]);
    float x2 = b2f(qkv[base + 64]);
    float inv = exp2f((float)d * -0.2076205059304600f);
    float ang = (float)pos * inv;
    float c = cosf(ang), s = sinf(ang);
    qkv[base]      = f2b(x1 * c - x2 * s);
    qkv[base + 64] = f2b(x2 * c + x1 * s);
  } else if (bid < 28672) {
    int b2 = bid - 24576;                    // 0..4095
    const int s0 = (b2 & 63) * 32, d0 = ((b2 >> 6) & 3) * 32;
    const int bh = b2 >> 8, b = bh >> 3, kvh = bh & 7;
    const int tx = tid & 31, ty = tid >> 5;  // 32 x 8
    const ushort* src = qkv + (size_t)(b * S_ + s0) * NQKV + VOFF + kvh * DH + d0;
#pragma unroll
    for (int j = 0; j < 32; j += 8)
      tile[ty + j][tx] = src[(size_t)(ty + j) * NQKV + tx];
    __syncthreads();
    ushort* dst = vt + (size_t)((b * HKV + kvh) * DH + d0) * S_ + s0;
#pragma unroll
    for (int j = 0; j < 32; j += 8)
      dst[(size_t)(ty + j) * S_ + tx] = tile[tx][ty + j];
  } else {
    int i = (bid - 28672) * 256 + tid;       // < 2097152 (4096*2048/4)
    float4 v = wo[i];
    wob[i] = make_ushort4(f2b(v.x), f2b(v.y), f2b(v.z), f2b(v.w));
  }
}

// ---------------- flash attention (causal, GQA) ----------------
// 8-wave blocks, kv-split (R9 structure, correctness-verified on HW): wave (qsub, kvhalf);
// LDS holds a PAIR of kv tiles; wave kvhalf computes tile 2j+kvhalf concurrently.
// Partner waves (2q, 2q+1) flash-merge (m,l,O) at pass end via LDS aliased onto dead K/V.
// R14 fixes vs R9: __launch_bounds__(512,2) -> VGPR cap 128 (R9's (512,4) capped at 64 ->
// 574MB scratch spill); in-place softmax on sacc (-16 VGPR, fold verified in R11).
__launch_bounds__(512, 2)
__global__ void attn_kernel(const ushort* __restrict__ qkv, const ushort* __restrict__ vt,
                            ushort* __restrict__ aout) {
  __shared__ ushort Ks[2][64 * DH];   // 32KB (slot = kvhalf); Ks[0] aliased as Es in epilogue
  __shared__ ushort Vts[2][DH * 64];  // 32KB; aliased as OX exchange in merge
  __shared__ ushort Ps[8][16 * 64];   // 16KB per-wave P; aliased as ML in merge
  const int tid = threadIdx.x, lane = tid & 63, w = tid >> 6;   // w 0..7
  const int qsub = w >> 1, kvhalf = w & 1;
  const int wg = blockIdx.x;
  const int swz = (wg & 7) * 64 + (wg >> 3);
  const int bh = swz >> 4, qi0 = swz & 15;
  const int b = bh >> 4, h = bh & 15, kvh = h >> 1;
  const int lr = lane & 15, lg = lane >> 4;

  const ushort* Kp = qkv + (size_t)(b * S_) * NQKV + KOFF + kvh * DH;
  const ushort* Vtp = vt + (size_t)(b * HKV + kvh) * DH * S_;
  ushort* Psw = &Ps[w][0];
  float* MLm = (float*)&Ps[0][0];          // [8][64] f32
  float* MLl = MLm + 512;                  // [8][64] f32

  // staging constants: pair = 2 tiles x (16KB K + 16KB V); 512 threads x 4 chunks x 16B each
  int koff[4], kb[4], voff[4], vb[4], tadd[4];
#pragma unroll
  for (int i = 0; i < 4; ++i) {
    int c = i * 512 + tid;                 // 0..2047
    int tp = c >> 10, cc = c & 1023;
    tadd[i] = tp;
    int krow = cc >> 4, kc = (cc & 15) * 8;
    koff[i] = krow * NQKV + kc;
    kb[i] = tp * 16384 + ((krow * 256 + kc * 2) ^ ((krow & 7) << 4));
    int vrow = cc >> 3, vc = (cc & 7) * 8;
    voff[i] = vrow * S_ + vc;
    vb[i] = tp * 16384 + ((vrow * 128 + vc * 2) ^ ((vrow & 7) << 4));
  }

  f32x4 zero = {0.0f, 0.0f, 0.0f, 0.0f};
  const float SCALE_LOG2E = 0.12751744116470802f;  // (1/sqrt(128)) * log2(e)

  for (int pass = 0; pass < 2; ++pass) {
    const int qi = pass ? (31 - qi0) : qi0;
    const int qt0 = qi * 64;
    const int qrow = qt0 + qsub * 16;
    const int q_lane = qrow + lr;
    const int ntiles = qi + 1;
    const int npairs = (ntiles + 1) >> 1;

    bf16x8 qf[4];
    {
      const ushort* Qp = qkv + (size_t)(b * S_ + qrow + lr) * NQKV + h * DH;
#pragma unroll
      for (int ds = 0; ds < 4; ++ds)
        qf[ds] = *(const bf16x8*)(Qp + ds * 32 + lg * 8);
    }

    float m_run = -1e30f, l_run = 0.0f;
    f32x4 acc_o[8];
#pragma unroll
    for (int n = 0; n < 8; ++n) acc_o[n] = zero;

    u32x4 kreg[4], vreg[4];

    // prologue: stage pair 0 (tiles 0, min(1,ntiles-1))
#pragma unroll
    for (int i = 0; i < 4; ++i) {
      int tt = tadd[i]; tt = (tt < ntiles) ? tt : (ntiles - 1);
      kreg[i] = *(const u32x4*)(Kp + (size_t)(tt * 64) * NQKV + koff[i]);
      vreg[i] = *(const u32x4*)(Vtp + (size_t)voff[i] + tt * 64);
    }
    __syncthreads();   // previous pass's LDS readers done
#pragma unroll
    for (int i = 0; i < 4; ++i) {
      *(u32x4*)((char*)&Ks[0][0] + kb[i]) = kreg[i];
      *(u32x4*)((char*)&Vts[0][0] + vb[i]) = vreg[i];
    }
    __syncthreads();

    for (int j = 0; j < npairs; ++j) {
      if (j + 1 < npairs) {
        const int tb = 2 * j + 2;
#pragma unroll
        for (int i = 0; i < 4; ++i) {
          int tt = tb + tadd[i]; tt = (tt < ntiles) ? tt : (ntiles - 1);
          kreg[i] = *(const u32x4*)(Kp + (size_t)(tt * 64) * NQKV + koff[i]);
          vreg[i] = *(const u32x4*)(Vtp + (size_t)voff[i] + tt * 64);
        }
      }

      const int t = 2 * j + kvhalf;
      if (t < ntiles) {
        const int kv0 = t * 64;
        const char* Ksw = (const char*)&Ks[kvhalf][0];
        const char* Vtsw = (const char*)&Vts[kvhalf][0];

        // S^T = K Q^T : sacc[ct] reg r -> kv = kv0+ct*16+lg*4+r, q = qrow+lr
        f32x4 sacc[4];
        __builtin_amdgcn_s_setprio(1);
#pragma unroll
        for (int ct = 0; ct < 4; ++ct) {
          sacc[ct] = zero;
#pragma unroll
          for (int ds = 0; ds < 4; ++ds) {
            int krow = ct * 16 + lr;
            int kbb = (krow * 256 + (ds * 32 + lg * 8) * 2) ^ ((krow & 7) << 4);
            bf16x8 kf = *(const bf16x8*)(Ksw + kbb);
            sacc[ct] = __builtin_amdgcn_mfma_f32_16x16x32_bf16(kf, qf[ds], sacc[ct], 0, 0, 0);
          }
        }
        __builtin_amdgcn_s_setprio(0);

        // per-lane online softmax (all 16 vals for q = q_lane), in-place on sacc
        float mx = -1e30f;
#pragma unroll
        for (int ct = 0; ct < 4; ++ct)
#pragma unroll
          for (int r = 0; r < 4; ++r) {
            int kv = kv0 + ct * 16 + lg * 4 + r;
            float x = sacc[ct][r] * SCALE_LOG2E;
            sacc[ct][r] = (kv <= q_lane) ? x : -1e30f;
            mx = fmaxf(mx, sacc[ct][r]);
          }
        mx = fmaxf(mx, __shfl_xor(mx, 16, 64));
        mx = fmaxf(mx, __shfl_xor(mx, 32, 64));
        if (!__all(mx <= m_run + 8.0f)) {
          float mnew = fmaxf(m_run, mx);
          float alpha = __builtin_amdgcn_exp2f(m_run - mnew);
          l_run *= alpha;
#pragma unroll
          for (int n = 0; n < 8; ++n)
#pragma unroll
            for (int r = 0; r < 4; ++r) acc_o[n][r] *= alpha;
          m_run = mnew;
        }
        float psum = 0.0f;
#pragma unroll
        for (int ct = 0; ct < 4; ++ct)
#pragma unroll
          for (int r = 0; r < 4; ++r) {
            float p = __builtin_amdgcn_exp2f(sacc[ct][r] - m_run);
            psum += p;
            int kvl = ct * 16 + lg * 4 + r;
            int pb = (lr * 128 + kvl * 2) ^ ((lr & 7) << 4);
            *(ushort*)((char*)Psw + pb) = f2b(p);
          }
        psum += __shfl_xor(psum, 16, 64);
        psum += __shfl_xor(psum, 32, 64);
        l_run += psum;

        asm volatile("s_waitcnt lgkmcnt(0)" ::: "memory");
        __builtin_amdgcn_sched_barrier(0);

        // O^T += V^T P : acc_o[n] reg r -> d = n*16+lg*4+r, q = qrow+lr
        __builtin_amdgcn_s_setprio(1);
#pragma unroll
        for (int ks = 0; ks < 2; ++ks) {
          int pb = (lr * 128 + (ks * 32 + lg * 8) * 2) ^ ((lr & 7) << 4);
          bf16x8 pf = *(const bf16x8*)((const char*)Psw + pb);
#pragma unroll
          for (int n = 0; n < 8; ++n) {
            int vrow = n * 16 + lr;
            int vbb = (vrow * 128 + (ks * 32 + lg * 8) * 2) ^ ((vrow & 7) << 4);
            bf16x8 vf = *(const bf16x8*)(Vtsw + vbb);
            acc_o[n] = __builtin_amdgcn_mfma_f32_16x16x32_bf16(vf, pf, acc_o[n], 0, 0, 0);
          }
        }
        __builtin_amdgcn_s_setprio(0);
      }

      if (j + 1 < npairs) {
        __syncthreads();
#pragma unroll
        for (int i = 0; i < 4; ++i) {
          *(u32x4*)((char*)&Ks[0][0] + kb[i]) = kreg[i];
          *(u32x4*)((char*)&Vts[0][0] + vb[i]) = vreg[i];
        }
        __syncthreads();
      }
    }

    // ---- flash-merge partner halves (waves 2q <- 2q+1), then epilogue ----
    __syncthreads();   // all compute done; K/V/Ps LDS now dead -> reusable
    MLm[w * 64 + lane] = m_run;
    MLl[w * 64 + lane] = l_run;
    char* ox = (char*)&Vts[0][0] + qsub * 8192;
    if (kvhalf == 1) {
#pragma unroll
      for (int n = 0; n < 8; ++n)
        *(f32x4*)(ox + lane * 128 + ((n * 16) ^ ((lane & 7) << 4))) = acc_o[n];
    }
    __syncthreads();
    if (kvhalf == 0) {
      float pm = MLm[(w + 1) * 64 + lane];
      float pl = MLl[(w + 1) * 64 + lane];
      float mstar = fmaxf(m_run, pm);
      float a0 = __builtin_amdgcn_exp2f(m_run - mstar);
      float a1 = __builtin_amdgcn_exp2f(pm - mstar);
      float lstar = l_run * a0 + pl * a1;
      float rl = 1.0f / lstar;
      // combined O -> Es [16 q][128 d] (aliased into Ks), then coalesced store
      char* Ew = (char*)&Ks[0][0] + qsub * 4096;
#pragma unroll
      for (int n = 0; n < 8; ++n) {
        f32x4 po = *(const f32x4*)(ox + lane * 128 + ((n * 16) ^ ((lane & 7) << 4)));
#pragma unroll
        for (int rp = 0; rp < 2; ++rp) {
          float v0 = (acc_o[n][2 * rp] * a0 + po[2 * rp] * a1) * rl;
          float v1 = (acc_o[n][2 * rp + 1] * a0 + po[2 * rp + 1] * a1) * rl;
          unsigned lo = f2b(v0), hi = f2b(v1);
          int d = n * 16 + lg * 4 + 2 * rp;
          int eb = (lr * 256 + d * 2) ^ ((lr & 7) << 4);
          *(unsigned*)(Ew + eb) = lo | (hi << 16);
        }
      }
      ushort* Ap = aout + (size_t)(b * S_ + qrow) * 2048 + h * DH;
#pragma unroll
      for (int it = 0; it < 4; ++it) {
        int c = it * 64 + lane;
        int q = c >> 4, k16 = c & 15;
        int rb = (q * 256 + k16 * 16) ^ ((q & 7) << 4);
        u32x4 v = *(const u32x4*)(Ew + rb);
        *(u32x4*)((char*)(Ap + (size_t)q * 2048) + k16 * 16) = v;
      }
    }
  }
}

// ---------------- launch ----------------
extern "C" void kernel_launch(void* const* d_in, const int* in_sizes, int n_in,
                              void* d_out, int out_size, void* d_ws, size_t ws_size,
                              hipStream_t stream) {
  const float* hs = (const float*)d_in[0];
  const float* wq = (const float*)d_in[2];
  const float* wk = (const float*)d_in[3];
  const float* wv = (const float*)d_in[4];
  const float* wo = (const float*)d_in[5];
  char* ws = (char*)d_ws;

  ushort* Xb   = (ushort*)(ws + 0);            // 33.5 MB (reused for Wo bf16 later)
  ushort* Wcat = (ushort*)(ws + 33554432);     // 33.5 MB (reused for Aout later)
  ushort* QKV  = (ushort*)(ws + 67108864);     // 33.5 MB
  ushort* Vt   = (ushort*)(ws + 100663296);    // 8.4 MB
  ushort* Wob  = Xb;
  ushort* Aout = Wcat;

  prep_cast_kernel<<<32768, 256, 0, stream>>>((const float4*)hs, wq, wk, wv,
                                              (ushort4*)Xb, (ushort4*)Wcat);
  gemm256<1><<<256, 512, 0, stream>>>(Xb, Wcat, QKV, 4096, 4096, 4096);
  rope_tv_wo_kernel<<<36864, 256, 0, stream>>>(QKV, Vt, (const float4*)wo, (ushort4*)Wob);
  attn_kernel<<<dim3(512), 512, 0, stream>>>(QKV, Vt, Aout);
  gemm256<0><<<256, 512, 0, stream>>>(Aout, Wob, (float*)d_out, 4096, 4096, 2048);
}

// Round 15
// 304.455 us; speedup vs baseline: 1.0568x; 1.0568x over previous
//
#include <hip/hip_runtime.h>
#include <cstdint>
#include <cstddef>

#define B_ 2
#define S_ 2048
#define NQKV 4096
#define HQ 16
#define HKV 8
#define DH 128
#define KOFF 2048
#define VOFF 3072

typedef __attribute__((ext_vector_type(4))) float f32x4;
typedef __attribute__((ext_vector_type(8))) short bf16x8;
typedef __attribute__((ext_vector_type(4))) unsigned int u32x4;
typedef const __attribute__((address_space(1))) void* gas1;
typedef __attribute__((address_space(3))) void* las3;
typedef __attribute__((address_space(3))) char* l3p;

__device__ __forceinline__ ushort f2b(float f) {
  union { float f; unsigned u; } x; x.f = f;
  return (ushort)((x.u + 0x7FFFu + ((x.u >> 16) & 1u)) >> 16);
}
__device__ __forceinline__ float b2f(ushort u) {
  union { unsigned u; float f; } x; x.u = ((unsigned)u) << 16; return x.f;
}

// ---------------- fused input casts: hs (f32->bf16) + concat(wq,wk,wv) ----------------
__global__ void prep_cast_kernel(const float4* __restrict__ hs,
                                 const float* __restrict__ wq, const float* __restrict__ wk,
                                 const float* __restrict__ wv,
                                 ushort4* __restrict__ xb, ushort4* __restrict__ wcat) {
  int bid = blockIdx.x;
  if (bid < 16384) {
    int i = bid * 256 + threadIdx.x;
    float4 v = hs[i];
    xb[i] = make_ushort4(f2b(v.x), f2b(v.y), f2b(v.z), f2b(v.w));
  } else {
    int i = (bid - 16384) * 256 + threadIdx.x;   // 0 .. 4096*1024
    int row = i >> 10, c4 = i & 1023;
    const float* src = (row < 2048) ? (wq + (size_t)row * 4096)
                     : (row < 3072) ? (wk + (size_t)(row - 2048) * 4096)
                                    : (wv + (size_t)(row - 3072) * 4096);
    float4 v = ((const float4*)src)[c4];
    wcat[i] = make_ushort4(f2b(v.x), f2b(v.y), f2b(v.z), f2b(v.w));
  }
}

// ---------------- GEMM: C[M,N] = A[M,K] * B[N,K]^T  (256x256 8-phase, asm ds_read) ----------------
// R6 schedule (verified fastest). Depth-2 variant measured SLOWER (R7).
#define DSR(dst, addr, off) asm volatile("ds_read_b128 %0, %1 offset:" #off : "=v"(dst) : "v"(addr) : "memory")
#define MFMA16(d, a, b) d = __builtin_amdgcn_mfma_f32_16x16x32_bf16(a, b, d, 0, 0, 0)

template<int OUT_BF16>
__launch_bounds__(512, 2)
__global__ void gemm256(const ushort* __restrict__ A, const ushort* __restrict__ Bm,
                        void* __restrict__ C, int M, int N, int K) {
  __shared__ __attribute__((aligned(16))) char lds[131072];
  const int tid = threadIdx.x;
  const int lane = tid & 63;
  const int w = tid >> 6;          // 0..7
  const int wm = w >> 2, wn = w & 3;
  const int lr = lane & 15, lg = lane >> 4;

  const int nwg = gridDim.x;
  const int cpx = nwg >> 3;
  const int wg = blockIdx.x;
  const int swz = (wg & 7) * cpx + (wg >> 3);
  const int NT = N >> 8;
  const int bm = swz / NT, bn = swz % NT;
  const int m0 = bm * 256, n0 = bn * 256;

  const ushort* Ab = A + (size_t)m0 * K;
  const ushort* Bb = Bm + (size_t)n0 * K;

  const int NKT = K >> 6;          // K-tiles of 64

  int srow[2], scol[2];
#pragma unroll
  for (int jj = 0; jj < 2; ++jj) {
    int lb = (jj * 512 + tid) * 16;
    int ls = lb ^ (((lb >> 7) & 7) << 4);
    srow[jj] = ls >> 7;            // 0..127
    scol[jj] = (ls & 127) >> 1;    // element col 0..63
  }
  const int ldsw = w * 1024;

  auto stage2 = [&](int t, int j) {
    t = (t < NKT - 1) ? t : (NKT - 1);       // tail clamp: re-stage same data (benign)
    const int slot = ((t & 1) << 16) + (j << 14);
    const ushort* src = (j == 1 || j == 2) ? Ab : Bb;
    const int h = (j >= 2) ? 128 : 0;
    const int k0 = t << 6;
#pragma unroll
    for (int jj = 0; jj < 2; ++jj) {
      const ushort* g = src + (size_t)(h + srow[jj]) * K + k0 + scol[jj];
      __builtin_amdgcn_global_load_lds((gas1)(const void*)g,
          (las3)(void*)(lds + slot + jj * 8192 + ldsw), 16, 0, 0);
    }
  };

  const unsigned lds0 = (unsigned)(size_t)(l3p)(void*)lds;
  const int swzc = (lr & 7) << 4;
  const int c0 = (lg * 16) ^ swzc;
  const int c1 = (64 + lg * 16) ^ swzc;
  const unsigned baseA = lds0 + 16384u + wm * 16384u + lr * 128u;
  const unsigned baseB = lds0 + ((wn >> 1) ? 49152u : 0u) + ((wn & 1) * 64 + lr) * 128u;

  f32x4 zero = {0.0f, 0.0f, 0.0f, 0.0f};
  f32x4 acc[8][4];
#pragma unroll
  for (int m = 0; m < 8; ++m)
#pragma unroll
    for (int n = 0; n < 4; ++n) acc[m][n] = zero;

  // prologue: tile0 all four slots + tile1 j0,j1  (12 loads); wait tile0 (youngest 4 may fly)
  stage2(0, 0); stage2(0, 1); stage2(0, 2); stage2(0, 3);
  stage2(1, 0); stage2(1, 1);
  asm volatile("s_waitcnt vmcnt(4)" ::: "memory");
  __builtin_amdgcn_s_barrier();

  for (int kt = 0; kt < NKT; ++kt) {
    const unsigned bo = (unsigned)((kt & 1) << 16);
    const unsigned aak0 = baseA + c0 + bo, aak1 = baseA + c1 + bo;
    const unsigned bak0 = baseB + c0 + bo, bak1 = baseB + c1 + bo;

    bf16x8 a0[2][4], a1[2][4], bq[2][2], bq2[2][2];

    // ---- P0: read a0(8) + b01(4) ; stage (kt+1, j2) ; MFMA Q(0,0)
    DSR(a0[0][0], aak0, 0);    DSR(a0[0][1], aak0, 2048);
    DSR(a0[0][2], aak0, 4096); DSR(a0[0][3], aak0, 6144);
    DSR(a0[1][0], aak1, 0);    DSR(a0[1][1], aak1, 2048);
    DSR(a0[1][2], aak1, 4096); DSR(a0[1][3], aak1, 6144);
    DSR(bq[0][0], bak0, 0);    DSR(bq[0][1], bak0, 2048);
    DSR(bq[1][0], bak1, 0);    DSR(bq[1][1], bak1, 2048);
    stage2(kt + 1, 2);
    asm volatile("s_waitcnt lgkmcnt(8)" ::: "memory");
    __builtin_amdgcn_s_barrier();
    asm volatile("s_waitcnt lgkmcnt(0)" ::: "memory");
    __builtin_amdgcn_sched_barrier(0);
    __builtin_amdgcn_s_setprio(1);
#pragma unroll
    for (int kk = 0; kk < 2; ++kk)
#pragma unroll
      for (int m = 0; m < 4; ++m) {
        MFMA16(acc[m][0], a0[kk][m], bq[kk][0]);
        MFMA16(acc[m][1], a0[kk][m], bq[kk][1]);
      }
    __builtin_amdgcn_s_setprio(0);
    __builtin_amdgcn_s_barrier();

    // ---- P1: read b23(4) ; stage (kt+1, j3) ; MFMA Q(0,1)
    DSR(bq2[0][0], bak0, 4096); DSR(bq2[0][1], bak0, 6144);
    DSR(bq2[1][0], bak1, 4096); DSR(bq2[1][1], bak1, 6144);
    stage2(kt + 1, 3);
    __builtin_amdgcn_s_barrier();
    asm volatile("s_waitcnt lgkmcnt(0)" ::: "memory");
    __builtin_amdgcn_sched_barrier(0);
    __builtin_amdgcn_s_setprio(1);
#pragma unroll
    for (int kk = 0; kk < 2; ++kk)
#pragma unroll
      for (int m = 0; m < 4; ++m) {
        MFMA16(acc[m][2], a0[kk][m], bq2[kk][0]);
        MFMA16(acc[m][3], a0[kk][m], bq2[kk][1]);
      }
    __builtin_amdgcn_s_setprio(0);
    __builtin_amdgcn_s_barrier();

    // ---- P2: read a1(8) ; stage (kt+2, j0) [drained @P1-end] ; MFMA Q(1,0)
    DSR(a1[0][0], aak0, 8192);  DSR(a1[0][1], aak0, 10240);
    DSR(a1[0][2], aak0, 12288); DSR(a1[0][3], aak0, 14336);
    DSR(a1[1][0], aak1, 8192);  DSR(a1[1][1], aak1, 10240);
    DSR(a1[1][2], aak1, 12288); DSR(a1[1][3], aak1, 14336);
    stage2(kt + 2, 0);
    __builtin_amdgcn_s_barrier();
    asm volatile("s_waitcnt lgkmcnt(0)" ::: "memory");
    __builtin_amdgcn_sched_barrier(0);
    __builtin_amdgcn_s_setprio(1);
#pragma unroll
    for (int kk = 0; kk < 2; ++kk)
#pragma unroll
      for (int m = 0; m < 4; ++m) {
        MFMA16(acc[m + 4][0], a1[kk][m], bq[kk][0]);
        MFMA16(acc[m + 4][1], a1[kk][m], bq[kk][1]);
      }
    __builtin_amdgcn_s_setprio(0);
    __builtin_amdgcn_s_barrier();

    // ---- P3: stage (kt+2, j1) [drained @P2-end] ; MFMA Q(1,1) ; vmcnt(4) at tile boundary
    stage2(kt + 2, 1);
    __builtin_amdgcn_s_barrier();
    __builtin_amdgcn_s_setprio(1);
#pragma unroll
    for (int kk = 0; kk < 2; ++kk)
#pragma unroll
      for (int m = 0; m < 4; ++m) {
        MFMA16(acc[m + 4][2], a1[kk][m], bq2[kk][0]);
        MFMA16(acc[m + 4][3], a1[kk][m], bq2[kk][1]);
      }
    __builtin_amdgcn_s_setprio(0);
    asm volatile("s_waitcnt vmcnt(4)" ::: "memory");
    __builtin_amdgcn_s_barrier();
  }

  // drain tail-clamped LDS-DMA before epilogue / endpgm
  asm volatile("s_waitcnt vmcnt(0)" ::: "memory");

  // epilogue
#pragma unroll
  for (int m = 0; m < 8; ++m) {
    const int row0 = m0 + wm * 128 + m * 16 + lg * 4;
#pragma unroll
    for (int n = 0; n < 4; ++n) {
      const int col = n0 + wn * 64 + n * 16 + lr;
#pragma unroll
      for (int r = 0; r < 4; ++r) {
        if (OUT_BF16) ((ushort*)C)[(size_t)(row0 + r) * N + col] = f2b(acc[m][n][r]);
        else          ((float*)C)[(size_t)(row0 + r) * N + col] = acc[m][n][r];
      }
    }
  }
}

// ---------------- fused RoPE (Q/K in-place) + V transpose + wo cast ----------------
__global__ void rope_tv_wo_kernel(ushort* __restrict__ qkv, ushort* __restrict__ vt,
                                  const float4* __restrict__ wo, ushort4* __restrict__ wob) {
  __shared__ ushort tile[32][33];
  int bid = blockIdx.x;
  int tid = threadIdx.x;
  if (bid < 24576) {
    int t = bid * 256 + tid;                 // < 4096*1536
    int row = t / 1536;
    int idx = t - row * 1536;
    int head = idx >> 6, d = idx & 63;
    int pos = row & (S_ - 1);
    int col = (head < HQ) ? (head * DH + d) : (KOFF + (head - HQ) * DH + d);
    size_t base = (size_t)row * NQKV + col;
    float x1 = b2f(qkv[base]);
    float x2 = b2f(qkv[base + 64]);
    float inv = exp2f((float)d * -0.2076205059304600f);
    float ang = (float)pos * inv;
    float c = cosf(ang), s = sinf(ang);
    qkv[base]      = f2b(x1 * c - x2 * s);
    qkv[base + 64] = f2b(x2 * c + x1 * s);
  } else if (bid < 28672) {
    int b2 = bid - 24576;                    // 0..4095
    const int s0 = (b2 & 63) * 32, d0 = ((b2 >> 6) & 3) * 32;
    const int bh = b2 >> 8, b = bh >> 3, kvh = bh & 7;
    const int tx = tid & 31, ty = tid >> 5;  // 32 x 8
    const ushort* src = qkv + (size_t)(b * S_ + s0) * NQKV + VOFF + kvh * DH + d0;
#pragma unroll
    for (int j = 0; j < 32; j += 8)
      tile[ty + j][tx] = src[(size_t)(ty + j) * NQKV + tx];
    __syncthreads();
    ushort* dst = vt + (size_t)((b * HKV + kvh) * DH + d0) * S_ + s0;
#pragma unroll
    for (int j = 0; j < 32; j += 8)
      dst[(size_t)(ty + j) * S_ + tx] = tile[tx][ty + j];
  } else {
    int i = (bid - 28672) * 256 + tid;       // < 2097152 (4096*2048/4)
    float4 v = wo[i];
    wob[i] = make_ushort4(f2b(v.x), f2b(v.y), f2b(v.z), f2b(v.w));
  }
}

// ---------------- flash attention (causal, GQA) ---- R8 structure + K/V double-buffer ----
// Swapped-operand form (verified R8/R10, ~70us): QK^T = mfma(K,Q); per-lane softmax;
// PV = mfma(V^T,P); Es transpose epilogue. R15 delta (ONLY change vs R10): K/V
// double-buffered -> ONE __syncthreads per kv-tile instead of two. Safety: iter t writes
// buf^1 whose last readers were iter t-1 (separated by t-1's trailing barrier); iter t+1's
// reads of buf^1 follow iter t's trailing barrier. Es aliases dead Ks (barrier before).
// Parked: (.,4) launch_bounds = VGPR-64 spill (R9/R11); kv-split 8-wave (R14); QK-ahead
// pipeline (R12) -- all regressed.
__launch_bounds__(256, 2)
__global__ void attn_kernel(const ushort* __restrict__ qkv, const ushort* __restrict__ vt,
                            ushort* __restrict__ aout) {
  __shared__ ushort Ks[2][64 * DH];   // 2x16KB, XOR-swizzled; Ks aliased as Es in epilogue
  __shared__ ushort Vts[2][DH * 64];  // 2x16KB, XOR-swizzled
  __shared__ ushort Ps[4][16 * 64];   // 8KB per-wave P [q16][kv64], XOR-swizzled
  const int tid = threadIdx.x, lane = tid & 63, w = tid >> 6;
  const int wg = blockIdx.x;
  const int swz = (wg & 7) * 64 + (wg >> 3);
  const int bh = swz >> 4, qi0 = swz & 15;
  const int b = bh >> 4, h = bh & 15, kvh = h >> 1;
  const int lr = lane & 15, lg = lane >> 4;

  const ushort* Kp = qkv + (size_t)(b * S_) * NQKV + KOFF + kvh * DH;
  const ushort* Vtp = vt + (size_t)(b * HKV + kvh) * DH * S_;
  ushort* Psw = &Ps[w][0];

  int koff[4], kb[4], voff[4], vb[4];
#pragma unroll
  for (int i = 0; i < 4; ++i) {
    int chunk = i * 256 + tid;
    int krow = chunk >> 4, kc = (chunk & 15) * 8;
    koff[i] = krow * NQKV + kc;
    kb[i] = (krow * 256 + kc * 2) ^ ((krow & 7) << 4);
    int vrow = chunk >> 3, vc = (chunk & 7) * 8;
    voff[i] = vrow * S_ + vc;
    vb[i] = (vrow * 128 + vc * 2) ^ ((vrow & 7) << 4);
  }

  f32x4 zero = {0.0f, 0.0f, 0.0f, 0.0f};
  const float SCALE_LOG2E = 0.12751744116470802f;  // (1/sqrt(128)) * log2(e)

  for (int pass = 0; pass < 2; ++pass) {
    const int qi = pass ? (31 - qi0) : qi0;
    const int qt0 = qi * 64;
    const int qrow = qt0 + w * 16;
    const int q_lane = qrow + lr;            // this lane's q row

    bf16x8 qf[4];
    {
      const ushort* Qp = qkv + (size_t)(b * S_ + qrow + lr) * NQKV + h * DH;
#pragma unroll
      for (int ds = 0; ds < 4; ++ds)
        qf[ds] = *(const bf16x8*)(Qp + ds * 32 + lg * 8);
    }

    float m_run = -1e30f, l_run = 0.0f;
    f32x4 acc_o[8];
#pragma unroll
    for (int n = 0; n < 8; ++n) acc_o[n] = zero;

    const int ntiles = qi + 1;
    u32x4 kreg[4], vreg[4];

    // prologue: stage tile0 -> buf0
#pragma unroll
    for (int i = 0; i < 4; ++i) {
      kreg[i] = *(const u32x4*)(Kp + koff[i]);
      vreg[i] = *(const u32x4*)(Vtp + voff[i]);
    }
    __syncthreads();   // previous pass's LDS readers (incl. Es) done
#pragma unroll
    for (int i = 0; i < 4; ++i) {
      *(u32x4*)((char*)Ks + kb[i]) = kreg[i];
      *(u32x4*)((char*)Vts + vb[i]) = vreg[i];
    }
    __syncthreads();

    for (int t = 0; t < ntiles; ++t) {
      const int kv0 = t * 64;
      const int cb = (t & 1) << 14;          // current buffer byte offset
      if (t + 1 < ntiles) {
        const int kv1 = kv0 + 64;
#pragma unroll
        for (int i = 0; i < 4; ++i) {
          kreg[i] = *(const u32x4*)(Kp + (size_t)kv1 * NQKV + koff[i]);
          vreg[i] = *(const u32x4*)(Vtp + kv1 + voff[i]);
        }
      }

      // S^T = K Q^T : sacc[ct] reg r -> kv = kv0+ct*16+lg*4+r, q = qrow+lr
      f32x4 sacc[4];
      __builtin_amdgcn_s_setprio(1);
#pragma unroll
      for (int ct = 0; ct < 4; ++ct) {
        sacc[ct] = zero;
#pragma unroll
        for (int ds = 0; ds < 4; ++ds) {
          int krow = ct * 16 + lr;
          int kbb = (krow * 256 + (ds * 32 + lg * 8) * 2) ^ ((krow & 7) << 4);
          bf16x8 kf = *(const bf16x8*)((const char*)Ks + cb + kbb);
          sacc[ct] = __builtin_amdgcn_mfma_f32_16x16x32_bf16(kf, qf[ds], sacc[ct], 0, 0, 0);
        }
      }
      __builtin_amdgcn_s_setprio(0);

      // per-lane online softmax over 16 values (all for q = q_lane)
      float sv[4][4];
      float mx = -1e30f;
#pragma unroll
      for (int ct = 0; ct < 4; ++ct)
#pragma unroll
        for (int r = 0; r < 4; ++r) {
          int kv = kv0 + ct * 16 + lg * 4 + r;
          float x = sacc[ct][r] * SCALE_LOG2E;
          sv[ct][r] = (kv <= q_lane) ? x : -1e30f;
          mx = fmaxf(mx, sv[ct][r]);
        }
      mx = fmaxf(mx, __shfl_xor(mx, 16, 64));
      mx = fmaxf(mx, __shfl_xor(mx, 32, 64));
      if (!__all(mx <= m_run + 8.0f)) {
        float mnew = fmaxf(m_run, mx);
        float alpha = __builtin_amdgcn_exp2f(m_run - mnew);
        l_run *= alpha;
#pragma unroll
        for (int n = 0; n < 8; ++n)
#pragma unroll
          for (int r = 0; r < 4; ++r) acc_o[n][r] *= alpha;
        m_run = mnew;
      }
      float psum = 0.0f;
#pragma unroll
      for (int ct = 0; ct < 4; ++ct)
#pragma unroll
        for (int r = 0; r < 4; ++r) {
          float p = __builtin_amdgcn_exp2f(sv[ct][r] - m_run);
          psum += p;
          int kvl = ct * 16 + lg * 4 + r;
          int pb = (lr * 128 + kvl * 2) ^ ((lr & 7) << 4);
          *(ushort*)((char*)Psw + pb) = f2b(p);
        }
      psum += __shfl_xor(psum, 16, 64);
      psum += __shfl_xor(psum, 32, 64);
      l_run += psum;

      asm volatile("s_waitcnt lgkmcnt(0)" ::: "memory");
      __builtin_amdgcn_sched_barrier(0);

      // O^T += V^T P : acc_o[n] reg r -> d = n*16+lg*4+r, q = qrow+lr
      __builtin_amdgcn_s_setprio(1);
#pragma unroll
      for (int ks = 0; ks < 2; ++ks) {
        int pb = (lr * 128 + (ks * 32 + lg * 8) * 2) ^ ((lr & 7) << 4);
        bf16x8 pf = *(const bf16x8*)((const char*)Psw + pb);
#pragma unroll
        for (int n = 0; n < 8; ++n) {
          int vrow = n * 16 + lr;
          int vbb = (vrow * 128 + (ks * 32 + lg * 8) * 2) ^ ((vrow & 7) << 4);
          bf16x8 vf = *(const bf16x8*)((const char*)Vts + cb + vbb);
          acc_o[n] = __builtin_amdgcn_mfma_f32_16x16x32_bf16(vf, pf, acc_o[n], 0, 0, 0);
        }
      }
      __builtin_amdgcn_s_setprio(0);

      // commit prefetched tile to the OTHER buffer; ONE barrier per tile.
      // (write-after-read safe: buf^1's last readers were iter t-1, behind its barrier)
      if (t + 1 < ntiles) {
        const int nb = cb ^ 16384;
#pragma unroll
        for (int i = 0; i < 4; ++i) {
          *(u32x4*)((char*)Ks + nb + kb[i]) = kreg[i];
          *(u32x4*)((char*)Vts + nb + vb[i]) = vreg[i];
        }
        __syncthreads();
      }
    }

    // epilogue: O^T (regs) -> Es (aliased on Ks, per-wave 4KB) -> coalesced global
    __syncthreads();   // all waves done reading Ks (last tile had no trailing barrier)
    float rl = 1.0f / l_run;
    char* Ew = (char*)Ks + w * 4096;
#pragma unroll
    for (int n = 0; n < 8; ++n)
#pragma unroll
      for (int rp = 0; rp < 2; ++rp) {
        unsigned lo = f2b(acc_o[n][2 * rp] * rl);
        unsigned hi = f2b(acc_o[n][2 * rp + 1] * rl);
        int d = n * 16 + lg * 4 + 2 * rp;
        int eb = (lr * 256 + d * 2) ^ ((lr & 7) << 4);
        *(unsigned*)(Ew + eb) = lo | (hi << 16);
      }
    ushort* Ap = aout + (size_t)(b * S_ + qrow) * 2048 + h * DH;
#pragma unroll
    for (int it = 0; it < 4; ++it) {
      int c = it * 64 + lane;
      int q = c >> 4, k16 = c & 15;
      int rb = (q * 256 + k16 * 16) ^ ((q & 7) << 4);
      u32x4 v = *(const u32x4*)(Ew + rb);
      *(u32x4*)((char*)(Ap + (size_t)q * 2048) + k16 * 16) = v;
    }
  }
}

// ---------------- launch ----------------
extern "C" void kernel_launch(void* const* d_in, const int* in_sizes, int n_in,
                              void* d_out, int out_size, void* d_ws, size_t ws_size,
                              hipStream_t stream) {
  const float* hs = (const float*)d_in[0];
  const float* wq = (const float*)d_in[2];
  const float* wk = (const float*)d_in[3];
  const float* wv = (const float*)d_in[4];
  const float* wo = (const float*)d_in[5];
  char* ws = (char*)d_ws;

  ushort* Xb   = (ushort*)(ws + 0);            // 33.5 MB (reused for Wo bf16 later)
  ushort* Wcat = (ushort*)(ws + 33554432);     // 33.5 MB (reused for Aout later)
  ushort* QKV  = (ushort*)(ws + 67108864);     // 33.5 MB
  ushort* Vt   = (ushort*)(ws + 100663296);    // 8.4 MB
  ushort* Wob  = Xb;
  ushort* Aout = Wcat;

  prep_cast_kernel<<<32768, 256, 0, stream>>>((const float4*)hs, wq, wk, wv,
                                              (ushort4*)Xb, (ushort4*)Wcat);
  gemm256<1><<<256, 512, 0, stream>>>(Xb, Wcat, QKV, 4096, 4096, 4096);
  rope_tv_wo_kernel<<<36864, 256, 0, stream>>>(QKV, Vt, (const float4*)wo, (ushort4*)Wob);
  attn_kernel<<<dim3(512), 256, 0, stream>>>(QKV, Vt, Aout);
  gemm256<0><<<256, 512, 0, stream>>>(Aout, Wob, (float*)d_out, 4096, 4096, 2048);
}